// Round 5
// baseline (1416.936 us; speedup 1.0000x reference)
//
#include <hip/hip_runtime.h>
#include <stdint.h>

#define PP 5
#define EE 400000
#define NN 50000
#define PN (PP*NN)            // 250000 rows (protocol,node)
#define EPT (PP*EE)           // 2,000,000 edges total
#define G2 408                // eproj blocks per protocol: 5*408=2040 <= 2048 resident (one batch)
#define NGRP (EE/64)          // 6250 groups of 64 slots per protocol
#define NBK ((NN+255)/256)    // 196 coarse buckets (256 nodes each) per protocol
#define NBKT (PP*NBK)         // 980 buckets total
#define CHUNK 4096            // edges per scatter block
#define NB2 ((EE+CHUNK-1)/CHUNK) // 98 scatter blocks per protocol
#define NPB 128               // nodes per agg block (divides 256 -> bucket-aligned)

typedef unsigned int u32;
typedef unsigned short u16;
typedef unsigned char u8;
typedef float f32x4 __attribute__((ext_vector_type(4)));
typedef short s16x8 __attribute__((ext_vector_type(8)));
union FAB { s16x8 v; u32 w[4]; };

__device__ __forceinline__ u16 f2bf(float x){
  u32 u = __float_as_uint(x);
  u32 r = (u + 0x7fffu + ((u>>16)&1u))>>16;
  return (u16)r;
}
__device__ __forceinline__ u32 packbf(float a, float b){
  return (u32)f2bf(a) | ((u32)f2bf(b)<<16);
}
__device__ __forceinline__ float bf2f(u32 b){ return __uint_as_float(b<<16); }
__device__ __forceinline__ float lrelu(float x){ return fmaxf(x,0.f)+0.2f*fminf(x,0.f); }

// ---------------- CSR build: atomic-free counting sort ----------------
// Pass 1: per-block LDS histogram over coarse buckets -> hist[p][bkt][blk]
__global__ __launch_bounds__(256) void k_bhist(const int* __restrict__ ei, u32* __restrict__ hist){
  __shared__ u32 sb[NBK];
  const int p=blockIdx.y, blk=blockIdx.x, t=threadIdx.x;
  for(int i=t;i<NBK;i+=256) sb[i]=0u;
  __syncthreads();
  const int* drow = ei + (size_t)(p*2+1)*EE;
  #pragma unroll
  for(int i=0;i<4;i++){
    int e = blk*CHUNK + i*1024 + t*4;
    if(e<EE){
      int4 d4=*(const int4*)&drow[e];
      atomicAdd(&sb[d4.x>>8],1u); atomicAdd(&sb[d4.y>>8],1u);
      atomicAdd(&sb[d4.z>>8],1u); atomicAdd(&sb[d4.w>>8],1u);
    }
  }
  __syncthreads();
  for(int i=t;i<NBK;i+=256) hist[((size_t)(p*NBK+i))*NB2 + blk]=sb[i];
}

// Pass 2a: per-(p,bucket) exclusive scan over its 98 block counts (in place); totals -> bcnt
__global__ __launch_bounds__(128) void k_bsum(u32* __restrict__ hist, u32* __restrict__ bcnt){
  __shared__ u32 s[128];
  const int g = blockIdx.y*NBK + blockIdx.x;
  const int t = threadIdx.x;
  u32 v = (t<NB2)? hist[(size_t)g*NB2+t] : 0u;
  s[t]=v; __syncthreads();
  for(int o=1;o<128;o<<=1){
    u32 x=(t>=o)?s[t-o]:0u;
    __syncthreads();
    s[t]+=x;
    __syncthreads();
  }
  if(t<NB2) hist[(size_t)g*NB2+t] = s[t]-v;
  if(t==127) bcnt[g]=s[127];
}

// Pass 2b: exclusive scan of 980 bucket totals -> boff (bucket stream bases)
__global__ __launch_bounds__(1024) void k_bscan(const u32* __restrict__ bcnt, u32* __restrict__ boff){
  __shared__ u32 s[1024];
  const int t=threadIdx.x;
  u32 v=(t<NBKT)?bcnt[t]:0u;
  s[t]=v; __syncthreads();
  for(int o=1;o<1024;o<<=1){
    u32 x=(t>=o)?s[t-o]:0u;
    __syncthreads();
    s[t]+=x;
    __syncthreads();
  }
  if(t<NBKT) boff[t]=s[t]-v;
  if(t==0) boff[NBKT]=(u32)EPT;
}

// Pass 3: scatter into bucket streams. Rank via block-private LDS cursors; NO global atomics.
__global__ __launch_bounds__(256) void k_bscatter2(const int* __restrict__ ei, const u32* __restrict__ boff,
                                                   const u32* __restrict__ hist, uint2* __restrict__ bedge){
  __shared__ u32 cur[NBK];
  const int p=blockIdx.y, blk=blockIdx.x, t=threadIdx.x;
  if(t<NBK) cur[t] = boff[p*NBK+t] + hist[((size_t)(p*NBK+t))*NB2 + blk];
  __syncthreads();
  const int* srow = ei + (size_t)(p*2  )*EE;
  const int* drow = ei + (size_t)(p*2+1)*EE;
  #pragma unroll
  for(int i=0;i<4;i++){
    int e = blk*CHUNK + i*1024 + t*4;
    if(e<EE){
      int4 s4=*(const int4*)&srow[e];
      int4 d4=*(const int4*)&drow[e];
      u32 p0=atomicAdd(&cur[d4.x>>8],1u);
      u32 p1=atomicAdd(&cur[d4.y>>8],1u);
      u32 p2=atomicAdd(&cur[d4.z>>8],1u);
      u32 p3=atomicAdd(&cur[d4.w>>8],1u);
      // pack: word0 = src (16b, NN<65536) | dest_local (8b) << 16 ; word1 = eid
      bedge[p0]=make_uint2((u32)s4.x|((u32)(d4.x&255)<<16),(u32)(e  ));
      bedge[p1]=make_uint2((u32)s4.y|((u32)(d4.y&255)<<16),(u32)(e+1));
      bedge[p2]=make_uint2((u32)s4.z|((u32)(d4.z&255)<<16),(u32)(e+2));
      bedge[p3]=make_uint2((u32)s4.w|((u32)(d4.w&255)<<16),(u32)(e+3));
    }
  }
}

// Pass 4: one block per bucket (256 consecutive nodes). Per-node hist + scan in LDS
// -> writes off[] directly; then places srcs16/eid/dst8 into the bucket's contiguous
// CSR range (L2-hot). k_split is fused away.
__global__ __launch_bounds__(256) void k_bfinal2(const uint2* __restrict__ bedge, const u32* __restrict__ boff,
                                                 u32* __restrict__ off, u16* __restrict__ srcs16,
                                                 u32* __restrict__ eid, u8* __restrict__ dst8){
  __shared__ u32 ncnt[256];
  __shared__ u32 lcur[256];
  const int p=blockIdx.y, b=blockIdx.x, t=threadIdx.x;
  const u32 g=(u32)(p*NBK+b);
  const u32 j0=boff[g], j1=boff[g+1], cnt=j1-j0;
  ncnt[t]=0u; __syncthreads();
  for(u32 i=t;i<cnt;i+=256){
    uint2 v=bedge[j0+i];
    atomicAdd(&ncnt[(v.x>>16)&255u],1u);
  }
  __syncthreads();
  u32 myc=ncnt[t];
  for(int o=1;o<256;o<<=1){
    u32 x=(t>=o)?ncnt[t-o]:0u;
    __syncthreads();
    ncnt[t]+=x;
    __syncthreads();
  }
  const u32 excl=ncnt[t]-myc;
  const int n0=b*256;
  if(n0+t<NN) off[(size_t)p*NN + n0 + t] = j0 + excl;
  if(g==NBKT-1 && t==0) off[PN]=(u32)EPT;
  lcur[t]=j0+excl;
  __syncthreads();
  for(u32 i=t;i<cnt;i+=256){
    uint2 v=bedge[j0+i];
    u32 dl=(v.x>>16)&255u;
    u32 pos=atomicAdd(&lcur[dl],1u);
    srcs16[pos]=(u16)(v.x&0xffffu);
    eid[pos]=v.y;
    dst8[pos]=(u8)dl;
  }
}

// ---------------- edge-feature projection via MFMA, CSR-slot order ----------------
__global__ __launch_bounds__(256) void k_eproj_mfma(
    const float* __restrict__ ea, const u32* __restrict__ eid,
    const float* __restrict__ we0, const float* __restrict__ we1,
    const float* __restrict__ we2, const float* __restrict__ we3,
    const float* __restrict__ we4, const float* __restrict__ we5,
    u16* __restrict__ ep0, u16* __restrict__ ep1, u16* __restrict__ ep2,
    u16* __restrict__ ep3, u16* __restrict__ ep4, u16* __restrict__ ep5,
    float* __restrict__ bpartP)
{
  __shared__ u16  sW[64*64];          // WcatT[m][k] bf16 (8 KB)
  __shared__ u16  sEpi[4*16*72];      // per-wave 16 edges x 72 bf16
  __shared__ float sRed[64];

  const int t=threadIdx.x, p=blockIdx.y;
  const int w=t>>6, L=t&63, e16=L&15, quad=L>>4;

  for(int i=t;i<2048;i+=256) ((u32*)sW)[i]=0u;
  if(t<64) sRed[t]=0.f;
  __syncthreads();

  #define FILLW(WPTR,FO,MOFF) { const float* wsrc=(WPTR)+(size_t)p*35*(FO); \
    for(int i=t;i<35*(FO);i+=256){ int k=i/(FO), f=i-k*(FO); \
      sW[((MOFF)+f)*64+k]=f2bf(wsrc[i]); } }
  FILLW(we0,8,0) FILLW(we1,8,8) FILLW(we2,2,16) FILLW(we3,8,24) FILLW(we4,8,32) FILLW(we5,15,48)
  #undef FILLW
  __syncthreads();

  // A fragments: A[m=lane&15 (+16*mt)][k=quad*8+j], held in regs for whole kernel
  FAB afr[4][2];
  #pragma unroll
  for(int mt=0;mt<4;mt++)
    #pragma unroll
    for(int kf=0;kf<2;kf++)
      afr[mt][kf].v = *(const s16x8*)&sW[(e16+16*mt)*64 + kf*32 + quad*8];

  float sumacc[16];
  #pragma unroll
  for(int i=0;i<16;i++) sumacc[i]=0.f;

  u16* const myEpi = &sEpi[w*1152];   // this wave's 16x72 region

  // software-prefetch the first iteration's edge id (blockIdx.x < G2 <= NGRP always)
  u32 eedge_next = eid[(size_t)p*EE + (size_t)blockIdx.x*64 + w*16 + e16];

  for(int g=blockIdx.x; g<NGRP; g+=G2){
    const size_t jbase = (size_t)p*EE + (size_t)g*64 + w*16;

    // consume prefetched eid; issue next iteration's eid load immediately so its
    // latency overlaps this iteration's row-gather + MFMA + stores
    const u32 eedge = eedge_next;
    {
      const int gn = g + G2;
      if(gn < NGRP)
        eedge_next = eid[(size_t)p*EE + (size_t)gn*64 + w*16 + e16];
    }

    // gather this lane's edge row segment straight to registers
    const float* row = ea + ((size_t)p*EE + eedge)*35;
    float v0=row[quad*8+0], v1=row[quad*8+1], v2=row[quad*8+2], v3=row[quad*8+3];
    float v4=row[quad*8+4], v5=row[quad*8+5], v6=row[quad*8+6], v7=row[quad*8+7];
    float b0=0.f,b1=0.f,b2=0.f;
    if(quad==0){ b0=row[32]; b1=row[33]; b2=row[34]; }

    FAB fa, fb;
    fa.w[0]=packbf(v0,v1); fa.w[1]=packbf(v2,v3);
    fa.w[2]=packbf(v4,v5); fa.w[3]=packbf(v6,v7);
    fb.w[0]=packbf(b0,b1); fb.w[1]=packbf(b2,0.f);
    fb.w[2]=0u; fb.w[3]=0u;

    f32x4 acc0={0,0,0,0},acc1={0,0,0,0},acc2={0,0,0,0},acc3={0,0,0,0};
    acc0=__builtin_amdgcn_mfma_f32_16x16x32_bf16(afr[0][0].v, fa.v, acc0,0,0,0);
    acc0=__builtin_amdgcn_mfma_f32_16x16x32_bf16(afr[0][1].v, fb.v, acc0,0,0,0);
    acc1=__builtin_amdgcn_mfma_f32_16x16x32_bf16(afr[1][0].v, fa.v, acc1,0,0,0);
    acc1=__builtin_amdgcn_mfma_f32_16x16x32_bf16(afr[1][1].v, fb.v, acc1,0,0,0);
    acc2=__builtin_amdgcn_mfma_f32_16x16x32_bf16(afr[2][0].v, fa.v, acc2,0,0,0);
    acc2=__builtin_amdgcn_mfma_f32_16x16x32_bf16(afr[2][1].v, fb.v, acc2,0,0,0);
    acc3=__builtin_amdgcn_mfma_f32_16x16x32_bf16(afr[3][0].v, fa.v, acc3,0,0,0);
    acc3=__builtin_amdgcn_mfma_f32_16x16x32_bf16(afr[3][1].v, fb.v, acc3,0,0,0);

    #pragma unroll
    for(int r=0;r<4;r++){ sumacc[r]+=acc0[r]; sumacc[4+r]+=acc1[r]; sumacc[8+r]+=acc2[r]; sumacc[12+r]+=acc3[r]; }

    // epilogue: C layout col=lane&15 (edge), row=quad*4+reg (weight col m) -> per-wave LDS transpose
    {
      u16* erow=&myEpi[e16*72];
      uint2 q;
      q.x=packbf(acc0[0],acc0[1]); q.y=packbf(acc0[2],acc0[3]);
      *(uint2*)(erow +  0 + 4*quad)=q;
      q.x=packbf(acc1[0],acc1[1]); q.y=packbf(acc1[2],acc1[3]);
      *(uint2*)(erow + 16 + 4*quad)=q;
      q.x=packbf(acc2[0],acc2[1]); q.y=packbf(acc2[2],acc2[3]);
      *(uint2*)(erow + 32 + 4*quad)=q;
      q.x=packbf(acc3[0],acc3[1]); q.y=packbf(acc3[2],acc3[3]);
      *(uint2*)(erow + 48 + 4*quad)=q;
    }
    // wave-internal LDS write->read ordering ONLY — do NOT drain vmcnt here:
    // keeping global loads/stores in flight across iterations is the MLP we need.
    asm volatile("s_waitcnt lgkmcnt(0)" ::: "memory");

    // coalesced stores (contiguous slot ranges per array)
    {
      const int grp=L>>4, e=L&15;
      const u16* erow=&myEpi[e*72];
      if(grp==0)      ((uint4*)ep0)[jbase+e]=*(const uint4*)(erow+ 0);
      else if(grp==1) ((uint4*)ep1)[jbase+e]=*(const uint4*)(erow+ 8);
      else if(grp==2) ((uint4*)ep3)[jbase+e]=*(const uint4*)(erow+24);
      else            ((uint4*)ep4)[jbase+e]=*(const uint4*)(erow+32);
      if(L<32){
        const int e2=L>>1, half=L&1;
        ((uint4*)ep5)[(jbase+e2)*2+half]=*(const uint4*)(&myEpi[e2*72]+48+8*half);
      } else if(L<48){
        const int e2=L-32;
        ((u32*)ep2)[jbase+e2]=*(const u32*)(&myEpi[e2*72]+16);
      }
    }
  }

  // column sums of fp32 projections (for self-loop mean vectors)
  #pragma unroll
  for(int i=0;i<16;i++){
    float v=sumacc[i];
    v+=__shfl_xor(v,1); v+=__shfl_xor(v,2); v+=__shfl_xor(v,4); v+=__shfl_xor(v,8);
    sumacc[i]=v;
  }
  if(e16==0){
    #pragma unroll
    for(int mt=0;mt<4;mt++)
      #pragma unroll
      for(int r=0;r<4;r++)
        atomicAdd(&sRed[16*mt+4*quad+r], sumacc[mt*4+r]);
  }
  __syncthreads();
  if(t<64) bpartP[((size_t)p*G2+blockIdx.x)*64+t]=sRed[t];
}

// parallel reduction of self-loop mean vectors: one block per (p,m) pair
__global__ __launch_bounds__(64) void k_selfvec3(const float* __restrict__ bpartP, float* __restrict__ selfvec){
  const int b=blockIdx.x;           // 0..PP*64-1
  const int p=b>>6, m=b&63, t=threadIdx.x;
  float s=0.f;
  for(int i=t;i<G2;i+=64) s+=bpartP[((size_t)p*G2+i)*64+m];
  s+=__shfl_xor(s,1); s+=__shfl_xor(s,2); s+=__shfl_xor(s,4);
  s+=__shfl_xor(s,8); s+=__shfl_xor(s,16); s+=__shfl_xor(s,32);
  if(t==0){
    s*=(1.f/EE);
    int l=-1, f=0;
    if(m<8){l=0;f=m;} else if(m<16){l=1;f=m-8;} else if(m<18){l=2;f=m-16;}
    else if(m>=24&&m<32){l=3;f=m-24;} else if(m>=32&&m<40){l=4;f=m-32;}
    else if(m>=48&&m<63){l=5;f=m-48;}
    if(l>=0) selfvec[(size_t)(l*5+p)*16+f]=s;
  }
}

// ---------------- first-layer node projection ----------------
template<int FI,int FO>
__global__ __launch_bounds__(256) void k_proj(
  const float* __restrict__ h, int hs,
  const float* __restrict__ wl, const float* __restrict__ wr,
  float* __restrict__ xl, float* __restrict__ xr)
{
  __shared__ float sl[FI*FO], sr[FI*FO];
  const int t=threadIdx.x, p=blockIdx.y;
  if(t<FI*FO){ sl[t]=wl[(size_t)p*FI*FO+t]; sr[t]=wr[(size_t)p*FI*FO+t]; }
  __syncthreads();
  const int n=blockIdx.x*256+t;
  if(n>=NN) return;
  float hv[FI];
  #pragma unroll
  for(int k=0;k<FI;k++) hv[k]=h[(size_t)n*hs+k];
  const size_t base=((size_t)p*NN+n)*FO;
  #pragma unroll
  for(int f=0;f<FO;f++){
    float al=0.f, ar=0.f;
    #pragma unroll
    for(int k=0;k<FI;k++){ al+=hv[k]*sl[k*FO+f]; ar+=hv[k]*sr[k*FO+f]; }
    xl[base+f]=al; xr[base+f]=ar;
  }
}

// ---------------- fused combine(prev layer) + projection(next layer) ----------------
// PO = output pitch of xl/xr (>= FO); pad lanes zeroed.
template<int FI,int FO,int PO,bool RELU>
__global__ __launch_bounds__(256) void k_comb(
  const float* __restrict__ partial, const float* __restrict__ b,
  const float* __restrict__ wl, const float* __restrict__ wr,
  float* __restrict__ xl, float* __restrict__ xr)
{
  __shared__ float sl[5*FI*FO], sr[5*FI*FO], sbias[FI];
  const int t=threadIdx.x;
  for(int i=t;i<5*FI*FO;i+=256){ sl[i]=wl[i]; sr[i]=wr[i]; }
  if(t<FI){ float s=0.f; for(int p=0;p<PP;p++) s+=b[p*FI+t]; sbias[t]=s; }
  __syncthreads();
  const int n=blockIdx.x*256+t;
  if(n>=NN) return;
  float h[FI];
  #pragma unroll
  for(int f=0;f<FI;f++) h[f]=sbias[f];
  #pragma unroll
  for(int p=0;p<PP;p++){
    const float* src=partial+((size_t)p*NN+n)*FI;
    #pragma unroll
    for(int f=0;f<FI;f++) h[f]+=src[f];
  }
  if(RELU){
    #pragma unroll
    for(int f=0;f<FI;f++) h[f]=fmaxf(h[f],0.f);
  }
  #pragma unroll
  for(int p=0;p<PP;p++){
    const float* wlp=&sl[p*FI*FO];
    const float* wrp=&sr[p*FI*FO];
    const size_t base=((size_t)p*NN+n)*PO;
    #pragma unroll
    for(int f=0;f<FO;f++){
      float al=0.f, ar=0.f;
      #pragma unroll
      for(int k=0;k<FI;k++){ al+=h[k]*wlp[k*FO+f]; ar+=h[k]*wrp[k*FO+f]; }
      xl[base+f]=al; xr[base+f]=ar;
    }
    #pragma unroll
    for(int f=FO;f<PO;f++){ xl[base+f]=0.f; xr[base+f]=0.f; }
  }
}

template<int FO,int PO>
__device__ __forceinline__ void load_row(const float* __restrict__ g, float* arr){
  if constexpr(FO==2){
    float2 v=*(const float2*)g; arr[0]=v.x; arr[1]=v.y;
  } else {
    #pragma unroll
    for(int c=0;c<(FO+3)/4;c++){
      float4 v=((const float4*)g)[c];
      arr[4*c]=v.x;
      if(4*c+1<FO) arr[4*c+1]=v.y;
      if(4*c+2<FO) arr[4*c+2]=v.z;
      if(4*c+3<FO) arr[4*c+3]=v.w;
    }
  }
}

// ---------------- edge-parallel gather aggregation ----------------
// One block owns NPB consecutive nodes: xr rows + CSR offsets staged in LDS,
// threads sweep the block's edge slots contiguously (coalesced srcs/ep/dst reads,
// independent iterations -> MLP), accumulate den/num via LDS float atomics.
// No degree-divergence tail, no dependent per-edge chains.
template<int FO,int EPAD,int PO>
__global__ __launch_bounds__(256) void k_agg2(
  const float* __restrict__ xl, const float* __restrict__ xr,
  const u32* __restrict__ off, const u16* __restrict__ srcs16,
  const u8* __restrict__ dst8, const u16* __restrict__ ep,
  const float* __restrict__ avec, const float* __restrict__ selfv,
  float* __restrict__ partial)
{
  __shared__ float sxr[NPB*FO];
  __shared__ float sden[NPB];
  __shared__ float snum[NPB*FO];
  __shared__ u32   soff[NPB+1];

  const int t=threadIdx.x, p=blockIdx.y;
  const int n0=blockIdx.x*NPB;
  const int nn=min(NPB, NN-n0);
  const int qoff=n0&255;           // bucket-local offset of this block's first node

  float av[FO];
  #pragma unroll
  for(int f=0;f<FO;f++) av[f]=avec[p*FO+f];

  if(t<=nn) soff[t]=off[(size_t)p*NN+n0+t];
  if(t<NPB){
    if(t<nn){
      float xrn[FO], xln[FO];
      load_row<FO,PO>(xr+((size_t)p*NN+n0+t)*PO, xrn);
      load_row<FO,PO>(xl+((size_t)p*NN+n0+t)*PO, xln);
      #pragma unroll
      for(int f=0;f<FO;f++) sxr[t*FO+f]=xrn[f];
      // self-loop term
      float e=0.f;
      #pragma unroll
      for(int f=0;f<FO;f++){ float m=xln[f]+xrn[f]+selfv[p*16+f]; e+=lrelu(m)*av[f]; }
      float ex=__expf(e);
      sden[t]=ex;
      #pragma unroll
      for(int f=0;f<FO;f++) snum[t*FO+f]=ex*xln[f];
    } else {
      sden[t]=0.f;
      #pragma unroll
      for(int f=0;f<FO;f++) snum[t*FO+f]=0.f;
    }
  }
  __syncthreads();

  const u32 j0=soff[0], j1=soff[nn];
  for(u32 j=j0+t; j<j1; j+=256){
    const u32 s=srcs16[j];
    const int dl=(int)dst8[j]-qoff;
    float epv[FO];
    if constexpr(EPAD==8){
      uint4 q=*(const uint4*)(ep+(size_t)j*8);
      epv[0]=bf2f(q.x&0xffffu); epv[1]=bf2f(q.x>>16);
      epv[2]=bf2f(q.y&0xffffu); epv[3]=bf2f(q.y>>16);
      epv[4]=bf2f(q.z&0xffffu); epv[5]=bf2f(q.z>>16);
      epv[6]=bf2f(q.w&0xffffu); epv[7]=bf2f(q.w>>16);
    } else if constexpr(EPAD==2){
      u32 q=*(const u32*)(ep+(size_t)j*2);
      epv[0]=bf2f(q&0xffffu); epv[1]=bf2f(q>>16);
    } else {
      const uint4* qq=(const uint4*)(ep+(size_t)j*16);
      uint4 q0=qq[0], q1=qq[1];
      u32 w[8]={q0.x,q0.y,q0.z,q0.w,q1.x,q1.y,q1.z,q1.w};
      #pragma unroll
      for(int i=0;i<8;i++){
        if(2*i  <FO) epv[2*i  ]=bf2f(w[i]&0xffffu);
        if(2*i+1<FO) epv[2*i+1]=bf2f(w[i]>>16);
      }
    }
    float xls[FO];
    load_row<FO,PO>(xl+((size_t)p*NN+s)*PO, xls);
    float e=0.f;
    #pragma unroll
    for(int f=0;f<FO;f++){ float m=xls[f]+sxr[dl*FO+f]+epv[f]; e+=lrelu(m)*av[f]; }
    const float ex=__expf(e);
    atomicAdd(&sden[dl],ex);
    #pragma unroll
    for(int f=0;f<FO;f++) atomicAdd(&snum[dl*FO+f], ex*xls[f]);
  }
  __syncthreads();

  if(t<nn){
    const float inv=1.f/sden[t];
    float* dst=partial+((size_t)p*NN+n0+t)*PO;
    #pragma unroll
    for(int f=0;f<FO;f++) dst[f]=snum[t*FO+f]*inv;
  }
}

// ---------------- final combine (d3 output, 15 wide, no relu) ----------------
__global__ __launch_bounds__(256) void k_final15(
  const float* __restrict__ partial, const float* __restrict__ b,
  float* __restrict__ out)
{
  __shared__ float sbias[15];
  const int t=threadIdx.x;
  if(t<15){ float s=0.f; for(int p=0;p<PP;p++) s+=b[p*15+t]; sbias[t]=s; }
  __syncthreads();
  const int n=blockIdx.x*256+t;
  if(n>=NN) return;
  float s[15];
  #pragma unroll
  for(int f=0;f<15;f++) s[f]=sbias[f];
  #pragma unroll
  for(int p=0;p<PP;p++){
    const float* src=partial+((size_t)p*NN+n)*16;
    #pragma unroll
    for(int f=0;f<15;f++) s[f]+=src[f];
  }
  #pragma unroll
  for(int f=0;f<15;f++) out[(size_t)n*15+f]=s[f];
}

// ---------------- launch ----------------
extern "C" void kernel_launch(void* const* d_in, const int* in_sizes, int n_in,
                              void* d_out, int out_size, void* d_ws, size_t ws_size,
                              hipStream_t stream)
{
  const float* x =(const float*)d_in[0];
  const float* ea=(const float*)d_in[1];
  const int*   ei=(const int*)d_in[2];
  auto W=[&](int l,int k)->const float*{ return (const float*)d_in[3+5*l+k]; };

  char* base=(char*)d_ws; size_t cur=0;
  auto alloc=[&](size_t bytes)->char*{ char* pp=base+cur; cur=(cur+bytes+255)&~(size_t)255; return pp; };
  u32*  off    =(u32*) alloc((size_t)(PN+1)*4);
  u32*  hist   =(u32*) alloc((size_t)NBKT*NB2*4);  // per-(bucket,block) counts -> bases
  u32*  bcnt   =(u32*) alloc((size_t)NBKT*4);
  u32*  boff   =(u32*) alloc((size_t)(NBKT+1)*4);
  u16*  srcs16 =(u16*) alloc((size_t)EPT*2);
  u32*  eid    =(u32*) alloc((size_t)EPT*4);
  u8*   dst8   =(u8*)  alloc((size_t)EPT);
  float* bpartP=(float*)alloc((size_t)PP*G2*64*4);
  float* selfvec=(float*)alloc(6*PP*16*4);
  float* xl    =(float*)alloc((size_t)PN*16*4);
  float* xr    =(float*)alloc((size_t)PN*16*4);
  float* partial=(float*)alloc((size_t)PN*16*4);
  u16*  ep0    =(u16*) alloc((size_t)EPT*8*2);
  u16*  ep1    =(u16*) alloc((size_t)EPT*8*2);
  u16*  ep2    =(u16*) alloc((size_t)EPT*2*2);
  u16*  ep3    =(u16*) alloc((size_t)EPT*8*2);
  u16*  ep4    =(u16*) alloc((size_t)EPT*8*2);
  u16*  ep5    =(u16*) alloc((size_t)EPT*16*2);
  // bedge aliases the first 16MB of ep5 (dead until k_eproj runs; stream-ordered)
  uint2* bedge =(uint2*)ep5;
  (void)ws_size; (void)in_sizes; (void)n_in; (void)out_size;

  dim3 b256(256);
  k_bhist    <<<dim3(NB2,PP),b256,0,stream>>>(ei,hist);
  k_bsum     <<<dim3(NBK,PP),dim3(128),0,stream>>>(hist,bcnt);
  k_bscan    <<<dim3(1),dim3(1024),0,stream>>>(bcnt,boff);
  k_bscatter2<<<dim3(NB2,PP),b256,0,stream>>>(ei,boff,hist,bedge);
  k_bfinal2  <<<dim3(NBK,PP),b256,0,stream>>>(bedge,boff,off,srcs16,eid,dst8);
  k_eproj_mfma<<<dim3(G2,PP),b256,0,stream>>>(ea,eid,
              W(0,2),W(1,2),W(2,2),W(3,2),W(4,2),W(5,2),
              ep0,ep1,ep2,ep3,ep4,ep5,bpartP);
  k_selfvec3<<<dim3(PP*64),dim3(64),0,stream>>>(bpartP,selfvec);

  dim3 gproj((NN+255)/256,PP), gagg((NN+NPB-1)/NPB,PP), gnode((NN+255)/256);

  // L0: e1 15->8
  k_proj<15,8><<<gproj,b256,0,stream>>>(x,15,W(0,0),W(0,1),xl,xr);
  k_agg2<8,8,8>   <<<gagg ,b256,0,stream>>>(xl,xr,off,srcs16,dst8,ep0,W(0,3),selfvec+0*80,partial);
  k_comb<8,8,8,true><<<gnode,b256,0,stream>>>(partial,W(0,4),W(1,0),W(1,1),xl,xr);   // relu(e1) -> proj e2
  k_agg2<8,8,8>   <<<gagg ,b256,0,stream>>>(xl,xr,off,srcs16,dst8,ep1,W(1,3),selfvec+1*80,partial);
  k_comb<8,2,2,true><<<gnode,b256,0,stream>>>(partial,W(1,4),W(2,0),W(2,1),xl,xr);   // relu(e2) -> proj e3
  k_agg2<2,2,2>   <<<gagg ,b256,0,stream>>>(xl,xr,off,srcs16,dst8,ep2,W(2,3),selfvec+2*80,partial);
  k_comb<2,8,8,false><<<gnode,b256,0,stream>>>(partial,W(2,4),W(3,0),W(3,1),xl,xr);  // NO relu after e3 -> proj d1
  k_agg2<8,8,8>   <<<gagg ,b256,0,stream>>>(xl,xr,off,srcs16,dst8,ep3,W(3,3),selfvec+3*80,partial);
  k_comb<8,8,8,true><<<gnode,b256,0,stream>>>(partial,W(3,4),W(4,0),W(4,1),xl,xr);   // relu(d1) -> proj d2
  k_agg2<8,8,8>   <<<gagg ,b256,0,stream>>>(xl,xr,off,srcs16,dst8,ep4,W(4,3),selfvec+4*80,partial);
  k_comb<8,15,16,true><<<gnode,b256,0,stream>>>(partial,W(4,4),W(5,0),W(5,1),xl,xr); // relu(d2) -> proj d3 (pitch 16)
  k_agg2<15,16,16><<<gagg ,b256,0,stream>>>(xl,xr,off,srcs16,dst8,ep5,W(5,3),selfvec+5*80,partial);
  k_final15<<<gnode,b256,0,stream>>>(partial,W(5,4),(float*)d_out);
}

// Round 6
// 803.796 us; speedup vs baseline: 1.7628x; 1.7628x over previous
//
#include <hip/hip_runtime.h>
#include <stdint.h>

#define PP 5
#define EE 400000
#define NN 50000
#define PN (PP*NN)            // 250000 rows (protocol,node)
#define EPT (PP*EE)           // 2,000,000 edges total
#define G2 408                // eproj blocks per protocol: 5*408=2040 <= 2048 resident (one batch)
#define NGRP (EE/64)          // 6250 groups of 64 slots per protocol
#define NBK ((NN+255)/256)    // 196 coarse buckets (256 nodes each) per protocol
#define NBKT (PP*NBK)         // 980 buckets total
#define CHUNK 4096            // edges per scatter block
#define NB2 ((EE+CHUNK-1)/CHUNK) // 98 scatter blocks per protocol

typedef unsigned int u32;
typedef unsigned short u16;
typedef unsigned char u8;
typedef float f32x4 __attribute__((ext_vector_type(4)));
typedef short s16x8 __attribute__((ext_vector_type(8)));
union FAB { s16x8 v; u32 w[4]; };

__device__ __forceinline__ u16 f2bf(float x){
  u32 u = __float_as_uint(x);
  u32 r = (u + 0x7fffu + ((u>>16)&1u))>>16;
  return (u16)r;
}
__device__ __forceinline__ u32 packbf(float a, float b){
  return (u32)f2bf(a) | ((u32)f2bf(b)<<16);
}
__device__ __forceinline__ float bf2f(u32 b){ return __uint_as_float(b<<16); }
__device__ __forceinline__ float lrelu(float x){ return fmaxf(x,0.f)+0.2f*fminf(x,0.f); }

// ---------------- CSR build: atomic-free counting sort ----------------
// Pass 1: per-block LDS histogram over coarse buckets -> hist[p][bkt][blk]
__global__ __launch_bounds__(256) void k_bhist(const int* __restrict__ ei, u32* __restrict__ hist){
  __shared__ u32 sb[NBK];
  const int p=blockIdx.y, blk=blockIdx.x, t=threadIdx.x;
  for(int i=t;i<NBK;i+=256) sb[i]=0u;
  __syncthreads();
  const int* drow = ei + (size_t)(p*2+1)*EE;
  #pragma unroll
  for(int i=0;i<4;i++){
    int e = blk*CHUNK + i*1024 + t*4;
    if(e<EE){
      int4 d4=*(const int4*)&drow[e];
      atomicAdd(&sb[d4.x>>8],1u); atomicAdd(&sb[d4.y>>8],1u);
      atomicAdd(&sb[d4.z>>8],1u); atomicAdd(&sb[d4.w>>8],1u);
    }
  }
  __syncthreads();
  for(int i=t;i<NBK;i+=256) hist[((size_t)(p*NBK+i))*NB2 + blk]=sb[i];
}

// Pass 2a: per-(p,bucket) exclusive scan over its 98 block counts (in place); totals -> bcnt
__global__ __launch_bounds__(128) void k_bsum(u32* __restrict__ hist, u32* __restrict__ bcnt){
  __shared__ u32 s[128];
  const int g = blockIdx.y*NBK + blockIdx.x;
  const int t = threadIdx.x;
  u32 v = (t<NB2)? hist[(size_t)g*NB2+t] : 0u;
  s[t]=v; __syncthreads();
  for(int o=1;o<128;o<<=1){
    u32 x=(t>=o)?s[t-o]:0u;
    __syncthreads();
    s[t]+=x;
    __syncthreads();
  }
  if(t<NB2) hist[(size_t)g*NB2+t] = s[t]-v;
  if(t==127) bcnt[g]=s[127];
}

// Pass 2b: exclusive scan of 980 bucket totals -> boff (bucket stream bases)
__global__ __launch_bounds__(1024) void k_bscan(const u32* __restrict__ bcnt, u32* __restrict__ boff){
  __shared__ u32 s[1024];
  const int t=threadIdx.x;
  u32 v=(t<NBKT)?bcnt[t]:0u;
  s[t]=v; __syncthreads();
  for(int o=1;o<1024;o<<=1){
    u32 x=(t>=o)?s[t-o]:0u;
    __syncthreads();
    s[t]+=x;
    __syncthreads();
  }
  if(t<NBKT) boff[t]=s[t]-v;
  if(t==0) boff[NBKT]=(u32)EPT;
}

// Pass 3: scatter into bucket streams. Rank via block-private LDS cursors; NO global atomics.
__global__ __launch_bounds__(256) void k_bscatter2(const int* __restrict__ ei, const u32* __restrict__ boff,
                                                   const u32* __restrict__ hist, uint2* __restrict__ bedge){
  __shared__ u32 cur[NBK];
  const int p=blockIdx.y, blk=blockIdx.x, t=threadIdx.x;
  if(t<NBK) cur[t] = boff[p*NBK+t] + hist[((size_t)(p*NBK+t))*NB2 + blk];
  __syncthreads();
  const int* srow = ei + (size_t)(p*2  )*EE;
  const int* drow = ei + (size_t)(p*2+1)*EE;
  #pragma unroll
  for(int i=0;i<4;i++){
    int e = blk*CHUNK + i*1024 + t*4;
    if(e<EE){
      int4 s4=*(const int4*)&srow[e];
      int4 d4=*(const int4*)&drow[e];
      u32 p0=atomicAdd(&cur[d4.x>>8],1u);
      u32 p1=atomicAdd(&cur[d4.y>>8],1u);
      u32 p2=atomicAdd(&cur[d4.z>>8],1u);
      u32 p3=atomicAdd(&cur[d4.w>>8],1u);
      // pack: word0 = src (16b, NN<65536) | dest_local (8b) << 16 ; word1 = eid
      bedge[p0]=make_uint2((u32)s4.x|((u32)(d4.x&255)<<16),(u32)(e  ));
      bedge[p1]=make_uint2((u32)s4.y|((u32)(d4.y&255)<<16),(u32)(e+1));
      bedge[p2]=make_uint2((u32)s4.z|((u32)(d4.z&255)<<16),(u32)(e+2));
      bedge[p3]=make_uint2((u32)s4.w|((u32)(d4.w&255)<<16),(u32)(e+3));
    }
  }
}

// Pass 4: one block per bucket (256 consecutive nodes). Per-node hist + scan in LDS
// -> writes off[] directly; then places srcs16/eid into the bucket's contiguous
// CSR range (L2-hot).
__global__ __launch_bounds__(256) void k_bfinal2(const uint2* __restrict__ bedge, const u32* __restrict__ boff,
                                                 u32* __restrict__ off, u16* __restrict__ srcs16,
                                                 u32* __restrict__ eid){
  __shared__ u32 ncnt[256];
  __shared__ u32 lcur[256];
  const int p=blockIdx.y, b=blockIdx.x, t=threadIdx.x;
  const u32 g=(u32)(p*NBK+b);
  const u32 j0=boff[g], j1=boff[g+1], cnt=j1-j0;
  ncnt[t]=0u; __syncthreads();
  for(u32 i=t;i<cnt;i+=256){
    uint2 v=bedge[j0+i];
    atomicAdd(&ncnt[(v.x>>16)&255u],1u);
  }
  __syncthreads();
  u32 myc=ncnt[t];
  for(int o=1;o<256;o<<=1){
    u32 x=(t>=o)?ncnt[t-o]:0u;
    __syncthreads();
    ncnt[t]+=x;
    __syncthreads();
  }
  const u32 excl=ncnt[t]-myc;
  const int n0=b*256;
  if(n0+t<NN) off[(size_t)p*NN + n0 + t] = j0 + excl;
  if(g==NBKT-1 && t==0) off[PN]=(u32)EPT;
  lcur[t]=j0+excl;
  __syncthreads();
  for(u32 i=t;i<cnt;i+=256){
    uint2 v=bedge[j0+i];
    u32 dl=(v.x>>16)&255u;
    u32 pos=atomicAdd(&lcur[dl],1u);
    srcs16[pos]=(u16)(v.x&0xffffu);
    eid[pos]=v.y;
  }
}

// ---------------- edge-feature projection via MFMA, CSR-slot order ----------------
__global__ __launch_bounds__(256) void k_eproj_mfma(
    const float* __restrict__ ea, const u32* __restrict__ eid,
    const float* __restrict__ we0, const float* __restrict__ we1,
    const float* __restrict__ we2, const float* __restrict__ we3,
    const float* __restrict__ we4, const float* __restrict__ we5,
    u16* __restrict__ ep0, u16* __restrict__ ep1, u16* __restrict__ ep2,
    u16* __restrict__ ep3, u16* __restrict__ ep4, u16* __restrict__ ep5,
    float* __restrict__ bpartP)
{
  __shared__ u16  sW[64*64];          // WcatT[m][k] bf16 (8 KB)
  __shared__ u16  sEpi[4*16*72];      // per-wave 16 edges x 72 bf16
  __shared__ float sRed[64];

  const int t=threadIdx.x, p=blockIdx.y;
  const int w=t>>6, L=t&63, e16=L&15, quad=L>>4;

  for(int i=t;i<2048;i+=256) ((u32*)sW)[i]=0u;
  if(t<64) sRed[t]=0.f;
  __syncthreads();

  #define FILLW(WPTR,FO,MOFF) { const float* wsrc=(WPTR)+(size_t)p*35*(FO); \
    for(int i=t;i<35*(FO);i+=256){ int k=i/(FO), f=i-k*(FO); \
      sW[((MOFF)+f)*64+k]=f2bf(wsrc[i]); } }
  FILLW(we0,8,0) FILLW(we1,8,8) FILLW(we2,2,16) FILLW(we3,8,24) FILLW(we4,8,32) FILLW(we5,15,48)
  #undef FILLW
  __syncthreads();

  // A fragments: A[m=lane&15 (+16*mt)][k=quad*8+j], held in regs for whole kernel
  FAB afr[4][2];
  #pragma unroll
  for(int mt=0;mt<4;mt++)
    #pragma unroll
    for(int kf=0;kf<2;kf++)
      afr[mt][kf].v = *(const s16x8*)&sW[(e16+16*mt)*64 + kf*32 + quad*8];

  float sumacc[16];
  #pragma unroll
  for(int i=0;i<16;i++) sumacc[i]=0.f;

  u16* const myEpi = &sEpi[w*1152];   // this wave's 16x72 region

  // software-prefetch the first iteration's edge id (blockIdx.x < G2 <= NGRP always)
  u32 eedge_next = eid[(size_t)p*EE + (size_t)blockIdx.x*64 + w*16 + e16];

  for(int g=blockIdx.x; g<NGRP; g+=G2){
    const size_t jbase = (size_t)p*EE + (size_t)g*64 + w*16;

    // consume prefetched eid; issue next iteration's eid load immediately so its
    // latency overlaps this iteration's row-gather + MFMA + stores
    const u32 eedge = eedge_next;
    {
      const int gn = g + G2;
      if(gn < NGRP)
        eedge_next = eid[(size_t)p*EE + (size_t)gn*64 + w*16 + e16];
    }

    // gather this lane's edge row segment straight to registers
    const float* row = ea + ((size_t)p*EE + eedge)*35;
    float v0=row[quad*8+0], v1=row[quad*8+1], v2=row[quad*8+2], v3=row[quad*8+3];
    float v4=row[quad*8+4], v5=row[quad*8+5], v6=row[quad*8+6], v7=row[quad*8+7];
    float b0=0.f,b1=0.f,b2=0.f;
    if(quad==0){ b0=row[32]; b1=row[33]; b2=row[34]; }

    FAB fa, fb;
    fa.w[0]=packbf(v0,v1); fa.w[1]=packbf(v2,v3);
    fa.w[2]=packbf(v4,v5); fa.w[3]=packbf(v6,v7);
    fb.w[0]=packbf(b0,b1); fb.w[1]=packbf(b2,0.f);
    fb.w[2]=0u; fb.w[3]=0u;

    f32x4 acc0={0,0,0,0},acc1={0,0,0,0},acc2={0,0,0,0},acc3={0,0,0,0};
    acc0=__builtin_amdgcn_mfma_f32_16x16x32_bf16(afr[0][0].v, fa.v, acc0,0,0,0);
    acc0=__builtin_amdgcn_mfma_f32_16x16x32_bf16(afr[0][1].v, fb.v, acc0,0,0,0);
    acc1=__builtin_amdgcn_mfma_f32_16x16x32_bf16(afr[1][0].v, fa.v, acc1,0,0,0);
    acc1=__builtin_amdgcn_mfma_f32_16x16x32_bf16(afr[1][1].v, fb.v, acc1,0,0,0);
    acc2=__builtin_amdgcn_mfma_f32_16x16x32_bf16(afr[2][0].v, fa.v, acc2,0,0,0);
    acc2=__builtin_amdgcn_mfma_f32_16x16x32_bf16(afr[2][1].v, fb.v, acc2,0,0,0);
    acc3=__builtin_amdgcn_mfma_f32_16x16x32_bf16(afr[3][0].v, fa.v, acc3,0,0,0);
    acc3=__builtin_amdgcn_mfma_f32_16x16x32_bf16(afr[3][1].v, fb.v, acc3,0,0,0);

    #pragma unroll
    for(int r=0;r<4;r++){ sumacc[r]+=acc0[r]; sumacc[4+r]+=acc1[r]; sumacc[8+r]+=acc2[r]; sumacc[12+r]+=acc3[r]; }

    // epilogue: C layout col=lane&15 (edge), row=quad*4+reg (weight col m) -> per-wave LDS transpose
    {
      u16* erow=&myEpi[e16*72];
      uint2 q;
      q.x=packbf(acc0[0],acc0[1]); q.y=packbf(acc0[2],acc0[3]);
      *(uint2*)(erow +  0 + 4*quad)=q;
      q.x=packbf(acc1[0],acc1[1]); q.y=packbf(acc1[2],acc1[3]);
      *(uint2*)(erow + 16 + 4*quad)=q;
      q.x=packbf(acc2[0],acc2[1]); q.y=packbf(acc2[2],acc2[3]);
      *(uint2*)(erow + 32 + 4*quad)=q;
      q.x=packbf(acc3[0],acc3[1]); q.y=packbf(acc3[2],acc3[3]);
      *(uint2*)(erow + 48 + 4*quad)=q;
    }
    // wave-internal LDS write->read ordering ONLY — do NOT drain vmcnt here:
    // keeping global loads/stores in flight across iterations is the MLP we need.
    asm volatile("s_waitcnt lgkmcnt(0)" ::: "memory");

    // coalesced stores (contiguous slot ranges per array)
    {
      const int grp=L>>4, e=L&15;
      const u16* erow=&myEpi[e*72];
      if(grp==0)      ((uint4*)ep0)[jbase+e]=*(const uint4*)(erow+ 0);
      else if(grp==1) ((uint4*)ep1)[jbase+e]=*(const uint4*)(erow+ 8);
      else if(grp==2) ((uint4*)ep3)[jbase+e]=*(const uint4*)(erow+24);
      else            ((uint4*)ep4)[jbase+e]=*(const uint4*)(erow+32);
      if(L<32){
        const int e2=L>>1, half=L&1;
        ((uint4*)ep5)[(jbase+e2)*2+half]=*(const uint4*)(&myEpi[e2*72]+48+8*half);
      } else if(L<48){
        const int e2=L-32;
        ((u32*)ep2)[jbase+e2]=*(const u32*)(&myEpi[e2*72]+16);
      }
    }
  }

  // column sums of fp32 projections (for self-loop mean vectors)
  #pragma unroll
  for(int i=0;i<16;i++){
    float v=sumacc[i];
    v+=__shfl_xor(v,1); v+=__shfl_xor(v,2); v+=__shfl_xor(v,4); v+=__shfl_xor(v,8);
    sumacc[i]=v;
  }
  if(e16==0){
    #pragma unroll
    for(int mt=0;mt<4;mt++)
      #pragma unroll
      for(int r=0;r<4;r++)
        atomicAdd(&sRed[16*mt+4*quad+r], sumacc[mt*4+r]);
  }
  __syncthreads();
  if(t<64) bpartP[((size_t)p*G2+blockIdx.x)*64+t]=sRed[t];
}

// parallel reduction of self-loop mean vectors: one block per (p,m) pair
__global__ __launch_bounds__(64) void k_selfvec3(const float* __restrict__ bpartP, float* __restrict__ selfvec){
  const int b=blockIdx.x;           // 0..PP*64-1
  const int p=b>>6, m=b&63, t=threadIdx.x;
  float s=0.f;
  for(int i=t;i<G2;i+=64) s+=bpartP[((size_t)p*G2+i)*64+m];
  s+=__shfl_xor(s,1); s+=__shfl_xor(s,2); s+=__shfl_xor(s,4);
  s+=__shfl_xor(s,8); s+=__shfl_xor(s,16); s+=__shfl_xor(s,32);
  if(t==0){
    s*=(1.f/EE);
    int l=-1, f=0;
    if(m<8){l=0;f=m;} else if(m<16){l=1;f=m-8;} else if(m<18){l=2;f=m-16;}
    else if(m>=24&&m<32){l=3;f=m-24;} else if(m>=32&&m<40){l=4;f=m-32;}
    else if(m>=48&&m<63){l=5;f=m-48;}
    if(l>=0) selfvec[(size_t)(l*5+p)*16+f]=s;
  }
}

// ---------------- first-layer node projection ----------------
template<int FI,int FO>
__global__ __launch_bounds__(256) void k_proj(
  const float* __restrict__ h, int hs,
  const float* __restrict__ wl, const float* __restrict__ wr,
  float* __restrict__ xl, float* __restrict__ xr)
{
  __shared__ float sl[FI*FO], sr[FI*FO];
  const int t=threadIdx.x, p=blockIdx.y;
  if(t<FI*FO){ sl[t]=wl[(size_t)p*FI*FO+t]; sr[t]=wr[(size_t)p*FI*FO+t]; }
  __syncthreads();
  const int n=blockIdx.x*256+t;
  if(n>=NN) return;
  float hv[FI];
  #pragma unroll
  for(int k=0;k<FI;k++) hv[k]=h[(size_t)n*hs+k];
  const size_t base=((size_t)p*NN+n)*FO;
  #pragma unroll
  for(int f=0;f<FO;f++){
    float al=0.f, ar=0.f;
    #pragma unroll
    for(int k=0;k<FI;k++){ al+=hv[k]*sl[k*FO+f]; ar+=hv[k]*sr[k*FO+f]; }
    xl[base+f]=al; xr[base+f]=ar;
  }
}

// ---------------- fused combine(prev layer) + projection(next layer) ----------------
// PO = output pitch of xl/xr (>= FO); pad lanes zeroed.
template<int FI,int FO,int PO,bool RELU>
__global__ __launch_bounds__(256) void k_comb(
  const float* __restrict__ partial, const float* __restrict__ b,
  const float* __restrict__ wl, const float* __restrict__ wr,
  float* __restrict__ xl, float* __restrict__ xr)
{
  __shared__ float sl[5*FI*FO], sr[5*FI*FO], sbias[FI];
  const int t=threadIdx.x;
  for(int i=t;i<5*FI*FO;i+=256){ sl[i]=wl[i]; sr[i]=wr[i]; }
  if(t<FI){ float s=0.f; for(int p=0;p<PP;p++) s+=b[p*FI+t]; sbias[t]=s; }
  __syncthreads();
  const int n=blockIdx.x*256+t;
  if(n>=NN) return;
  float h[FI];
  #pragma unroll
  for(int f=0;f<FI;f++) h[f]=sbias[f];
  #pragma unroll
  for(int p=0;p<PP;p++){
    const float* src=partial+((size_t)p*NN+n)*FI;
    #pragma unroll
    for(int f=0;f<FI;f++) h[f]+=src[f];
  }
  if(RELU){
    #pragma unroll
    for(int f=0;f<FI;f++) h[f]=fmaxf(h[f],0.f);
  }
  #pragma unroll
  for(int p=0;p<PP;p++){
    const float* wlp=&sl[p*FI*FO];
    const float* wrp=&sr[p*FI*FO];
    const size_t base=((size_t)p*NN+n)*PO;
    #pragma unroll
    for(int f=0;f<FO;f++){
      float al=0.f, ar=0.f;
      #pragma unroll
      for(int k=0;k<FI;k++){ al+=h[k]*wlp[k*FO+f]; ar+=h[k]*wrp[k*FO+f]; }
      xl[base+f]=al; xr[base+f]=ar;
    }
    #pragma unroll
    for(int f=FO;f<PO;f++){ xl[base+f]=0.f; xr[base+f]=0.f; }
  }
}

template<int FO,int PO>
__device__ __forceinline__ void load_row(const float* __restrict__ g, float* arr){
  if constexpr(FO==2){
    float2 v=*(const float2*)g; arr[0]=v.x; arr[1]=v.y;
  } else {
    #pragma unroll
    for(int c=0;c<(FO+3)/4;c++){
      float4 v=((const float4*)g)[c];
      arr[4*c]=v.x;
      if(4*c+1<FO) arr[4*c+1]=v.y;
      if(4*c+2<FO) arr[4*c+2]=v.z;
      if(4*c+3<FO) arr[4*c+3]=v.w;
    }
  }
}

// ---------------- per-layer gather aggregation (4 lanes per row; no atomics) ----------------
template<int FO,int EPAD,int PO>
__global__ __launch_bounds__(256) void k_agg(
  const float* __restrict__ xl, const float* __restrict__ xr,
  const u32* __restrict__ off, const u16* __restrict__ srcs16,
  const u16* __restrict__ ep, const float* __restrict__ avec,
  const float* __restrict__ selfv, float* __restrict__ partial)
{
  const int t=threadIdx.x, p=blockIdx.y;
  const int n=blockIdx.x*64+(t>>2), sub=t&3;
  if(n>=NN) return;
  const int r=p*NN+n;
  float av[FO], xln[FO], xrn[FO];
  #pragma unroll
  for(int f=0;f<FO;f++) av[f]=avec[p*FO+f];
  load_row<FO,PO>(xl+(size_t)r*PO, xln);
  load_row<FO,PO>(xr+(size_t)r*PO, xrn);

  float den=0.f, num[FO];
  #pragma unroll
  for(int f=0;f<FO;f++) num[f]=0.f;
  if(sub==0){
    float e=0.f;
    #pragma unroll
    for(int f=0;f<FO;f++){ float m=xln[f]+xrn[f]+selfv[p*16+f]; e+=lrelu(m)*av[f]; }
    float ex=__expf(e);
    den=ex;
    #pragma unroll
    for(int f=0;f<FO;f++) num[f]=ex*xln[f];
  }
  const u32 j1=off[r+1];
  for(u32 j=off[r]+sub;j<j1;j+=4){
    const u32 s=srcs16[j];
    float epv[FO];
    if constexpr(EPAD==8){
      uint4 q=*(const uint4*)(ep+(size_t)j*8);
      epv[0]=bf2f(q.x&0xffffu); epv[1]=bf2f(q.x>>16);
      epv[2]=bf2f(q.y&0xffffu); epv[3]=bf2f(q.y>>16);
      epv[4]=bf2f(q.z&0xffffu); epv[5]=bf2f(q.z>>16);
      epv[6]=bf2f(q.w&0xffffu); epv[7]=bf2f(q.w>>16);
    } else if constexpr(EPAD==2){
      u32 q=*(const u32*)(ep+(size_t)j*2);
      epv[0]=bf2f(q&0xffffu); epv[1]=bf2f(q>>16);
    } else {
      const uint4* qq=(const uint4*)(ep+(size_t)j*16);
      uint4 q0=qq[0], q1=qq[1];
      u32 w[8]={q0.x,q0.y,q0.z,q0.w,q1.x,q1.y,q1.z,q1.w};
      #pragma unroll
      for(int i=0;i<8;i++){
        if(2*i  <FO) epv[2*i  ]=bf2f(w[i]&0xffffu);
        if(2*i+1<FO) epv[2*i+1]=bf2f(w[i]>>16);
      }
    }
    float xls[FO];
    load_row<FO,PO>(xl+((size_t)p*NN+s)*PO, xls);
    float e=0.f;
    #pragma unroll
    for(int f=0;f<FO;f++){ float m=xls[f]+xrn[f]+epv[f]; e+=lrelu(m)*av[f]; }
    const float ex=__expf(e);
    den+=ex;
    #pragma unroll
    for(int f=0;f<FO;f++) num[f]+=ex*xls[f];
  }
  den+=__shfl_xor(den,1); den+=__shfl_xor(den,2);
  #pragma unroll
  for(int f=0;f<FO;f++){ num[f]+=__shfl_xor(num[f],1); num[f]+=__shfl_xor(num[f],2); }
  if(sub==0){
    const float inv=1.f/den;
    float* dst=partial+(size_t)r*PO;
    #pragma unroll
    for(int f=0;f<FO;f++) dst[f]=num[f]*inv;
  }
}

// ---------------- final combine (d3 output, 15 wide, no relu) ----------------
__global__ __launch_bounds__(256) void k_final15(
  const float* __restrict__ partial, const float* __restrict__ b,
  float* __restrict__ out)
{
  __shared__ float sbias[15];
  const int t=threadIdx.x;
  if(t<15){ float s=0.f; for(int p=0;p<PP;p++) s+=b[p*15+t]; sbias[t]=s; }
  __syncthreads();
  const int n=blockIdx.x*256+t;
  if(n>=NN) return;
  float s[15];
  #pragma unroll
  for(int f=0;f<15;f++) s[f]=sbias[f];
  #pragma unroll
  for(int p=0;p<PP;p++){
    const float* src=partial+((size_t)p*NN+n)*16;
    #pragma unroll
    for(int f=0;f<15;f++) s[f]+=src[f];
  }
  #pragma unroll
  for(int f=0;f<15;f++) out[(size_t)n*15+f]=s[f];
}

// ---------------- launch ----------------
extern "C" void kernel_launch(void* const* d_in, const int* in_sizes, int n_in,
                              void* d_out, int out_size, void* d_ws, size_t ws_size,
                              hipStream_t stream)
{
  const float* x =(const float*)d_in[0];
  const float* ea=(const float*)d_in[1];
  const int*   ei=(const int*)d_in[2];
  auto W=[&](int l,int k)->const float*{ return (const float*)d_in[3+5*l+k]; };

  char* base=(char*)d_ws; size_t cur=0;
  auto alloc=[&](size_t bytes)->char*{ char* pp=base+cur; cur=(cur+bytes+255)&~(size_t)255; return pp; };
  u32*  off    =(u32*) alloc((size_t)(PN+1)*4);
  u32*  hist   =(u32*) alloc((size_t)NBKT*NB2*4);  // per-(bucket,block) counts -> bases
  u32*  bcnt   =(u32*) alloc((size_t)NBKT*4);
  u32*  boff   =(u32*) alloc((size_t)(NBKT+1)*4);
  u16*  srcs16 =(u16*) alloc((size_t)EPT*2);
  u32*  eid    =(u32*) alloc((size_t)EPT*4);
  float* bpartP=(float*)alloc((size_t)PP*G2*64*4);
  float* selfvec=(float*)alloc(6*PP*16*4);
  float* xl    =(float*)alloc((size_t)PN*16*4);
  float* xr    =(float*)alloc((size_t)PN*16*4);
  float* partial=(float*)alloc((size_t)PN*16*4);
  u16*  ep0    =(u16*) alloc((size_t)EPT*8*2);
  u16*  ep1    =(u16*) alloc((size_t)EPT*8*2);
  u16*  ep2    =(u16*) alloc((size_t)EPT*2*2);
  u16*  ep3    =(u16*) alloc((size_t)EPT*8*2);
  u16*  ep4    =(u16*) alloc((size_t)EPT*8*2);
  u16*  ep5    =(u16*) alloc((size_t)EPT*16*2);
  // bedge aliases the first 16MB of ep5 (dead until k_eproj runs; stream-ordered)
  uint2* bedge =(uint2*)ep5;
  (void)ws_size; (void)in_sizes; (void)n_in; (void)out_size;

  dim3 b256(256);
  k_bhist    <<<dim3(NB2,PP),b256,0,stream>>>(ei,hist);
  k_bsum     <<<dim3(NBK,PP),dim3(128),0,stream>>>(hist,bcnt);
  k_bscan    <<<dim3(1),dim3(1024),0,stream>>>(bcnt,boff);
  k_bscatter2<<<dim3(NB2,PP),b256,0,stream>>>(ei,boff,hist,bedge);
  k_bfinal2  <<<dim3(NBK,PP),b256,0,stream>>>(bedge,boff,off,srcs16,eid);
  k_eproj_mfma<<<dim3(G2,PP),b256,0,stream>>>(ea,eid,
              W(0,2),W(1,2),W(2,2),W(3,2),W(4,2),W(5,2),
              ep0,ep1,ep2,ep3,ep4,ep5,bpartP);
  k_selfvec3<<<dim3(PP*64),dim3(64),0,stream>>>(bpartP,selfvec);

  dim3 gproj((NN+255)/256,PP), gagg((NN+63)/64,PP), gnode((NN+255)/256);

  // L0: e1 15->8
  k_proj<15,8><<<gproj,b256,0,stream>>>(x,15,W(0,0),W(0,1),xl,xr);
  k_agg<8,8,8>   <<<gagg ,b256,0,stream>>>(xl,xr,off,srcs16,ep0,W(0,3),selfvec+0*80,partial);
  k_comb<8,8,8,true><<<gnode,b256,0,stream>>>(partial,W(0,4),W(1,0),W(1,1),xl,xr);   // relu(e1) -> proj e2
  k_agg<8,8,8>   <<<gagg ,b256,0,stream>>>(xl,xr,off,srcs16,ep1,W(1,3),selfvec+1*80,partial);
  k_comb<8,2,2,true><<<gnode,b256,0,stream>>>(partial,W(1,4),W(2,0),W(2,1),xl,xr);   // relu(e2) -> proj e3
  k_agg<2,2,2>   <<<gagg ,b256,0,stream>>>(xl,xr,off,srcs16,ep2,W(2,3),selfvec+2*80,partial);
  k_comb<2,8,8,false><<<gnode,b256,0,stream>>>(partial,W(2,4),W(3,0),W(3,1),xl,xr);  // NO relu after e3 -> proj d1
  k_agg<8,8,8>   <<<gagg ,b256,0,stream>>>(xl,xr,off,srcs16,ep3,W(3,3),selfvec+3*80,partial);
  k_comb<8,8,8,true><<<gnode,b256,0,stream>>>(partial,W(3,4),W(4,0),W(4,1),xl,xr);   // relu(d1) -> proj d2
  k_agg<8,8,8>   <<<gagg ,b256,0,stream>>>(xl,xr,off,srcs16,ep4,W(4,3),selfvec+4*80,partial);
  k_comb<8,15,16,true><<<gnode,b256,0,stream>>>(partial,W(4,4),W(5,0),W(5,1),xl,xr); // relu(d2) -> proj d3 (pitch 16)
  k_agg<15,16,16><<<gagg ,b256,0,stream>>>(xl,xr,off,srcs16,ep5,W(5,3),selfvec+5*80,partial);
  k_final15<<<gnode,b256,0,stream>>>(partial,W(5,4),(float*)d_out);
}

// Round 7
// 802.296 us; speedup vs baseline: 1.7661x; 1.0019x over previous
//
#include <hip/hip_runtime.h>
#include <stdint.h>

#define PP 5
#define EE 400000
#define NN 50000
#define PN (PP*NN)            // 250000 rows (protocol,node)
#define EPT (PP*EE)           // 2,000,000 edges total
#define G2 408                // eproj blocks per protocol: 5*408=2040 <= 2048 resident (one batch)
#define NGRP (EE/64)          // 6250 groups of 64 slots per protocol
#define NBK ((NN+255)/256)    // 196 coarse buckets (256 nodes each) per protocol
#define NBKT (PP*NBK)         // 980 buckets total
#define CHUNK 4096            // edges per scatter block
#define NB2 ((EE+CHUNK-1)/CHUNK) // 98 scatter blocks per protocol
#define BCAP 3072             // bfinal2 LDS edge capacity (avg bucket ~2040)

typedef unsigned int u32;
typedef unsigned short u16;
typedef unsigned char u8;
typedef float f32x4 __attribute__((ext_vector_type(4)));
typedef short s16x8 __attribute__((ext_vector_type(8)));
union FAB { s16x8 v; u32 w[4]; };

__device__ __forceinline__ u16 f2bf(float x){
  u32 u = __float_as_uint(x);
  u32 r = (u + 0x7fffu + ((u>>16)&1u))>>16;
  return (u16)r;
}
__device__ __forceinline__ u32 packbf(float a, float b){
  return (u32)f2bf(a) | ((u32)f2bf(b)<<16);
}
__device__ __forceinline__ float bf2f(u32 b){ return __uint_as_float(b<<16); }
__device__ __forceinline__ float lrelu(float x){ return fmaxf(x,0.f)+0.2f*fminf(x,0.f); }

// ---------------- CSR build: atomic-free counting sort ----------------
// Pass 1: per-block LDS histogram over coarse buckets -> hist[p][bkt][blk]
__global__ __launch_bounds__(256) void k_bhist(const int* __restrict__ ei, u32* __restrict__ hist){
  __shared__ u32 sb[NBK];
  const int p=blockIdx.y, blk=blockIdx.x, t=threadIdx.x;
  for(int i=t;i<NBK;i+=256) sb[i]=0u;
  __syncthreads();
  const int* drow = ei + (size_t)(p*2+1)*EE;
  #pragma unroll
  for(int i=0;i<4;i++){
    int e = blk*CHUNK + i*1024 + t*4;
    if(e<EE){
      int4 d4=*(const int4*)&drow[e];
      atomicAdd(&sb[d4.x>>8],1u); atomicAdd(&sb[d4.y>>8],1u);
      atomicAdd(&sb[d4.z>>8],1u); atomicAdd(&sb[d4.w>>8],1u);
    }
  }
  __syncthreads();
  for(int i=t;i<NBK;i+=256) hist[((size_t)(p*NBK+i))*NB2 + blk]=sb[i];
}

// Pass 2a: per-(p,bucket) exclusive scan over its 98 block counts (in place); totals -> bcnt
__global__ __launch_bounds__(128) void k_bsum(u32* __restrict__ hist, u32* __restrict__ bcnt){
  __shared__ u32 s[128];
  const int g = blockIdx.y*NBK + blockIdx.x;
  const int t = threadIdx.x;
  u32 v = (t<NB2)? hist[(size_t)g*NB2+t] : 0u;
  s[t]=v; __syncthreads();
  for(int o=1;o<128;o<<=1){
    u32 x=(t>=o)?s[t-o]:0u;
    __syncthreads();
    s[t]+=x;
    __syncthreads();
  }
  if(t<NB2) hist[(size_t)g*NB2+t] = s[t]-v;
  if(t==127) bcnt[g]=s[127];
}

// Pass 2b: exclusive scan of 980 bucket totals -> boff (bucket stream bases)
__global__ __launch_bounds__(1024) void k_bscan(const u32* __restrict__ bcnt, u32* __restrict__ boff){
  __shared__ u32 s[1024];
  const int t=threadIdx.x;
  u32 v=(t<NBKT)?bcnt[t]:0u;
  s[t]=v; __syncthreads();
  for(int o=1;o<1024;o<<=1){
    u32 x=(t>=o)?s[t-o]:0u;
    __syncthreads();
    s[t]+=x;
    __syncthreads();
  }
  if(t<NBKT) boff[t]=s[t]-v;
  if(t==0) boff[NBKT]=(u32)EPT;
}

// Pass 3: scatter into bucket streams. Rank via block-private LDS cursors; NO global atomics.
__global__ __launch_bounds__(256) void k_bscatter2(const int* __restrict__ ei, const u32* __restrict__ boff,
                                                   const u32* __restrict__ hist, uint2* __restrict__ bedge){
  __shared__ u32 cur[NBK];
  const int p=blockIdx.y, blk=blockIdx.x, t=threadIdx.x;
  if(t<NBK) cur[t] = boff[p*NBK+t] + hist[((size_t)(p*NBK+t))*NB2 + blk];
  __syncthreads();
  const int* srow = ei + (size_t)(p*2  )*EE;
  const int* drow = ei + (size_t)(p*2+1)*EE;
  #pragma unroll
  for(int i=0;i<4;i++){
    int e = blk*CHUNK + i*1024 + t*4;
    if(e<EE){
      int4 s4=*(const int4*)&srow[e];
      int4 d4=*(const int4*)&drow[e];
      u32 p0=atomicAdd(&cur[d4.x>>8],1u);
      u32 p1=atomicAdd(&cur[d4.y>>8],1u);
      u32 p2=atomicAdd(&cur[d4.z>>8],1u);
      u32 p3=atomicAdd(&cur[d4.w>>8],1u);
      // pack: word0 = src (16b, NN<65536) | dest_local (8b) << 16 ; word1 = eid
      bedge[p0]=make_uint2((u32)s4.x|((u32)(d4.x&255)<<16),(u32)(e  ));
      bedge[p1]=make_uint2((u32)s4.y|((u32)(d4.y&255)<<16),(u32)(e+1));
      bedge[p2]=make_uint2((u32)s4.z|((u32)(d4.z&255)<<16),(u32)(e+2));
      bedge[p3]=make_uint2((u32)s4.w|((u32)(d4.w&255)<<16),(u32)(e+3));
    }
  }
}

// Pass 4: one block per bucket (256 consecutive nodes). Bucket edges staged in LDS
// (single global read); per-node hist + scan in LDS -> writes off[] directly; then
// places srcs16/eid into the bucket's contiguous CSR range (L2-hot).
__global__ __launch_bounds__(256) void k_bfinal2(const uint2* __restrict__ bedge, const u32* __restrict__ boff,
                                                 u32* __restrict__ off, u16* __restrict__ srcs16,
                                                 u32* __restrict__ eid){
  __shared__ u32 ncnt[256];
  __shared__ u32 lcur[256];
  __shared__ uint2 sedge[BCAP];     // 24 KB
  const int p=blockIdx.y, b=blockIdx.x, t=threadIdx.x;
  const u32 g=(u32)(p*NBK+b);
  const u32 j0=boff[g], j1=boff[g+1], cnt=j1-j0;
  const bool fit=(cnt<=BCAP);
  ncnt[t]=0u; __syncthreads();
  for(u32 i=t;i<cnt;i+=256){
    uint2 v=bedge[j0+i];
    if(fit) sedge[i]=v;
    atomicAdd(&ncnt[(v.x>>16)&255u],1u);
  }
  __syncthreads();
  u32 myc=ncnt[t];
  for(int o=1;o<256;o<<=1){
    u32 x=(t>=o)?ncnt[t-o]:0u;
    __syncthreads();
    ncnt[t]+=x;
    __syncthreads();
  }
  const u32 excl=ncnt[t]-myc;
  const int n0=b*256;
  if(n0+t<NN) off[(size_t)p*NN + n0 + t] = j0 + excl;
  if(g==NBKT-1 && t==0) off[PN]=(u32)EPT;
  lcur[t]=j0+excl;
  __syncthreads();
  for(u32 i=t;i<cnt;i+=256){
    uint2 v = fit ? sedge[i] : bedge[j0+i];
    u32 dl=(v.x>>16)&255u;
    u32 pos=atomicAdd(&lcur[dl],1u);
    srcs16[pos]=(u16)(v.x&0xffffu);
    eid[pos]=v.y;
  }
}

// ---------------- edge-feature projection via MFMA, CSR-slot order ----------------
__global__ __launch_bounds__(256) void k_eproj_mfma(
    const float* __restrict__ ea, const u32* __restrict__ eid,
    const float* __restrict__ we0, const float* __restrict__ we1,
    const float* __restrict__ we2, const float* __restrict__ we3,
    const float* __restrict__ we4, const float* __restrict__ we5,
    u16* __restrict__ ep0, u16* __restrict__ ep1, u16* __restrict__ ep2,
    u16* __restrict__ ep3, u16* __restrict__ ep4, u16* __restrict__ ep5,
    float* __restrict__ bpartP)
{
  __shared__ u16  sW[64*64];          // WcatT[m][k] bf16 (8 KB)
  __shared__ u16  sEpi[4*16*72];      // per-wave 16 edges x 72 bf16
  __shared__ float sRed[64];

  const int t=threadIdx.x, p=blockIdx.y;
  const int w=t>>6, L=t&63, e16=L&15, quad=L>>4;

  for(int i=t;i<2048;i+=256) ((u32*)sW)[i]=0u;
  if(t<64) sRed[t]=0.f;
  __syncthreads();

  #define FILLW(WPTR,FO,MOFF) { const float* wsrc=(WPTR)+(size_t)p*35*(FO); \
    for(int i=t;i<35*(FO);i+=256){ int k=i/(FO), f=i-k*(FO); \
      sW[((MOFF)+f)*64+k]=f2bf(wsrc[i]); } }
  FILLW(we0,8,0) FILLW(we1,8,8) FILLW(we2,2,16) FILLW(we3,8,24) FILLW(we4,8,32) FILLW(we5,15,48)
  #undef FILLW
  __syncthreads();

  // A fragments: A[m=lane&15 (+16*mt)][k=quad*8+j], held in regs for whole kernel
  FAB afr[4][2];
  #pragma unroll
  for(int mt=0;mt<4;mt++)
    #pragma unroll
    for(int kf=0;kf<2;kf++)
      afr[mt][kf].v = *(const s16x8*)&sW[(e16+16*mt)*64 + kf*32 + quad*8];

  float sumacc[16];
  #pragma unroll
  for(int i=0;i<16;i++) sumacc[i]=0.f;

  u16* const myEpi = &sEpi[w*1152];   // this wave's 16x72 region

  // software-prefetch the first iteration's edge id (blockIdx.x < G2 <= NGRP always)
  u32 eedge_next = eid[(size_t)p*EE + (size_t)blockIdx.x*64 + w*16 + e16];

  for(int g=blockIdx.x; g<NGRP; g+=G2){
    const size_t jbase = (size_t)p*EE + (size_t)g*64 + w*16;

    // consume prefetched eid; issue next iteration's eid load immediately so its
    // latency overlaps this iteration's row-gather + MFMA + stores
    const u32 eedge = eedge_next;
    {
      const int gn = g + G2;
      if(gn < NGRP)
        eedge_next = eid[(size_t)p*EE + (size_t)gn*64 + w*16 + e16];
    }

    // gather this lane's edge row segment straight to registers
    const float* row = ea + ((size_t)p*EE + eedge)*35;
    float v0=row[quad*8+0], v1=row[quad*8+1], v2=row[quad*8+2], v3=row[quad*8+3];
    float v4=row[quad*8+4], v5=row[quad*8+5], v6=row[quad*8+6], v7=row[quad*8+7];
    float b0=0.f,b1=0.f,b2=0.f;
    if(quad==0){ b0=row[32]; b1=row[33]; b2=row[34]; }

    FAB fa, fb;
    fa.w[0]=packbf(v0,v1); fa.w[1]=packbf(v2,v3);
    fa.w[2]=packbf(v4,v5); fa.w[3]=packbf(v6,v7);
    fb.w[0]=packbf(b0,b1); fb.w[1]=packbf(b2,0.f);
    fb.w[2]=0u; fb.w[3]=0u;

    f32x4 acc0={0,0,0,0},acc1={0,0,0,0},acc2={0,0,0,0},acc3={0,0,0,0};
    acc0=__builtin_amdgcn_mfma_f32_16x16x32_bf16(afr[0][0].v, fa.v, acc0,0,0,0);
    acc0=__builtin_amdgcn_mfma_f32_16x16x32_bf16(afr[0][1].v, fb.v, acc0,0,0,0);
    acc1=__builtin_amdgcn_mfma_f32_16x16x32_bf16(afr[1][0].v, fa.v, acc1,0,0,0);
    acc1=__builtin_amdgcn_mfma_f32_16x16x32_bf16(afr[1][1].v, fb.v, acc1,0,0,0);
    acc2=__builtin_amdgcn_mfma_f32_16x16x32_bf16(afr[2][0].v, fa.v, acc2,0,0,0);
    acc2=__builtin_amdgcn_mfma_f32_16x16x32_bf16(afr[2][1].v, fb.v, acc2,0,0,0);
    acc3=__builtin_amdgcn_mfma_f32_16x16x32_bf16(afr[3][0].v, fa.v, acc3,0,0,0);
    acc3=__builtin_amdgcn_mfma_f32_16x16x32_bf16(afr[3][1].v, fb.v, acc3,0,0,0);

    #pragma unroll
    for(int r=0;r<4;r++){ sumacc[r]+=acc0[r]; sumacc[4+r]+=acc1[r]; sumacc[8+r]+=acc2[r]; sumacc[12+r]+=acc3[r]; }

    // epilogue: C layout col=lane&15 (edge), row=quad*4+reg (weight col m) -> per-wave LDS transpose
    {
      u16* erow=&myEpi[e16*72];
      uint2 q;
      q.x=packbf(acc0[0],acc0[1]); q.y=packbf(acc0[2],acc0[3]);
      *(uint2*)(erow +  0 + 4*quad)=q;
      q.x=packbf(acc1[0],acc1[1]); q.y=packbf(acc1[2],acc1[3]);
      *(uint2*)(erow + 16 + 4*quad)=q;
      q.x=packbf(acc2[0],acc2[1]); q.y=packbf(acc2[2],acc2[3]);
      *(uint2*)(erow + 32 + 4*quad)=q;
      q.x=packbf(acc3[0],acc3[1]); q.y=packbf(acc3[2],acc3[3]);
      *(uint2*)(erow + 48 + 4*quad)=q;
    }
    // wave-internal LDS write->read ordering ONLY — do NOT drain vmcnt here:
    // keeping global loads/stores in flight across iterations is the MLP we need.
    asm volatile("s_waitcnt lgkmcnt(0)" ::: "memory");

    // coalesced stores (contiguous slot ranges per array)
    {
      const int grp=L>>4, e=L&15;
      const u16* erow=&myEpi[e*72];
      if(grp==0)      ((uint4*)ep0)[jbase+e]=*(const uint4*)(erow+ 0);
      else if(grp==1) ((uint4*)ep1)[jbase+e]=*(const uint4*)(erow+ 8);
      else if(grp==2) ((uint4*)ep3)[jbase+e]=*(const uint4*)(erow+24);
      else            ((uint4*)ep4)[jbase+e]=*(const uint4*)(erow+32);
      if(L<32){
        const int e2=L>>1, half=L&1;
        ((uint4*)ep5)[(jbase+e2)*2+half]=*(const uint4*)(&myEpi[e2*72]+48+8*half);
      } else if(L<48){
        const int e2=L-32;
        ((u32*)ep2)[jbase+e2]=*(const u32*)(&myEpi[e2*72]+16);
      }
    }
  }

  // column sums of fp32 projections (for self-loop mean vectors)
  #pragma unroll
  for(int i=0;i<16;i++){
    float v=sumacc[i];
    v+=__shfl_xor(v,1); v+=__shfl_xor(v,2); v+=__shfl_xor(v,4); v+=__shfl_xor(v,8);
    sumacc[i]=v;
  }
  if(e16==0){
    #pragma unroll
    for(int mt=0;mt<4;mt++)
      #pragma unroll
      for(int r=0;r<4;r++)
        atomicAdd(&sRed[16*mt+4*quad+r], sumacc[mt*4+r]);
  }
  __syncthreads();
  if(t<64) bpartP[((size_t)p*G2+blockIdx.x)*64+t]=sRed[t];
}

// parallel reduction of self-loop mean vectors: one block per (p,m) pair
__global__ __launch_bounds__(64) void k_selfvec3(const float* __restrict__ bpartP, float* __restrict__ selfvec){
  const int b=blockIdx.x;           // 0..PP*64-1
  const int p=b>>6, m=b&63, t=threadIdx.x;
  float s=0.f;
  for(int i=t;i<G2;i+=64) s+=bpartP[((size_t)p*G2+i)*64+m];
  s+=__shfl_xor(s,1); s+=__shfl_xor(s,2); s+=__shfl_xor(s,4);
  s+=__shfl_xor(s,8); s+=__shfl_xor(s,16); s+=__shfl_xor(s,32);
  if(t==0){
    s*=(1.f/EE);
    int l=-1, f=0;
    if(m<8){l=0;f=m;} else if(m<16){l=1;f=m-8;} else if(m<18){l=2;f=m-16;}
    else if(m>=24&&m<32){l=3;f=m-24;} else if(m>=32&&m<40){l=4;f=m-32;}
    else if(m>=48&&m<63){l=5;f=m-48;}
    if(l>=0) selfvec[(size_t)(l*5+p)*16+f]=s;
  }
}

// ---------------- first-layer node projection ----------------
template<int FI,int FO>
__global__ __launch_bounds__(256) void k_proj(
  const float* __restrict__ h, int hs,
  const float* __restrict__ wl, const float* __restrict__ wr,
  float* __restrict__ xl, float* __restrict__ xr)
{
  __shared__ float sl[FI*FO], sr[FI*FO];
  const int t=threadIdx.x, p=blockIdx.y;
  if(t<FI*FO){ sl[t]=wl[(size_t)p*FI*FO+t]; sr[t]=wr[(size_t)p*FI*FO+t]; }
  __syncthreads();
  const int n=blockIdx.x*256+t;
  if(n>=NN) return;
  float hv[FI];
  #pragma unroll
  for(int k=0;k<FI;k++) hv[k]=h[(size_t)n*hs+k];
  const size_t base=((size_t)p*NN+n)*FO;
  #pragma unroll
  for(int f=0;f<FO;f++){
    float al=0.f, ar=0.f;
    #pragma unroll
    for(int k=0;k<FI;k++){ al+=hv[k]*sl[k*FO+f]; ar+=hv[k]*sr[k*FO+f]; }
    xl[base+f]=al; xr[base+f]=ar;
  }
}

// ---------------- fused combine(prev layer) + projection(next layer) ----------------
// PO = output pitch of xl/xr (>= FO); pad lanes zeroed.
template<int FI,int FO,int PO,bool RELU>
__global__ __launch_bounds__(256) void k_comb(
  const float* __restrict__ partial, const float* __restrict__ b,
  const float* __restrict__ wl, const float* __restrict__ wr,
  float* __restrict__ xl, float* __restrict__ xr)
{
  __shared__ float sl[5*FI*FO], sr[5*FI*FO], sbias[FI];
  const int t=threadIdx.x;
  for(int i=t;i<5*FI*FO;i+=256){ sl[i]=wl[i]; sr[i]=wr[i]; }
  if(t<FI){ float s=0.f; for(int p=0;p<PP;p++) s+=b[p*FI+t]; sbias[t]=s; }
  __syncthreads();
  const int n=blockIdx.x*256+t;
  if(n>=NN) return;
  float h[FI];
  #pragma unroll
  for(int f=0;f<FI;f++) h[f]=sbias[f];
  #pragma unroll
  for(int p=0;p<PP;p++){
    const float* src=partial+((size_t)p*NN+n)*FI;
    #pragma unroll
    for(int f=0;f<FI;f++) h[f]+=src[f];
  }
  if(RELU){
    #pragma unroll
    for(int f=0;f<FI;f++) h[f]=fmaxf(h[f],0.f);
  }
  #pragma unroll
  for(int p=0;p<PP;p++){
    const float* wlp=&sl[p*FI*FO];
    const float* wrp=&sr[p*FI*FO];
    const size_t base=((size_t)p*NN+n)*PO;
    #pragma unroll
    for(int f=0;f<FO;f++){
      float al=0.f, ar=0.f;
      #pragma unroll
      for(int k=0;k<FI;k++){ al+=h[k]*wlp[k*FO+f]; ar+=h[k]*wrp[k*FO+f]; }
      xl[base+f]=al; xr[base+f]=ar;
    }
    #pragma unroll
    for(int f=FO;f<PO;f++){ xl[base+f]=0.f; xr[base+f]=0.f; }
  }
}

template<int FO,int PO>
__device__ __forceinline__ void load_row(const float* __restrict__ g, float* arr){
  if constexpr(FO==2){
    float2 v=*(const float2*)g; arr[0]=v.x; arr[1]=v.y;
  } else {
    #pragma unroll
    for(int c=0;c<(FO+3)/4;c++){
      float4 v=((const float4*)g)[c];
      arr[4*c]=v.x;
      if(4*c+1<FO) arr[4*c+1]=v.y;
      if(4*c+2<FO) arr[4*c+2]=v.z;
      if(4*c+3<FO) arr[4*c+3]=v.w;
    }
  }
}

template<int FO,int EPAD>
__device__ __forceinline__ void load_ep(const u16* __restrict__ ep, u32 j, float* epv){
  if constexpr(EPAD==8){
    uint4 q=*(const uint4*)(ep+(size_t)j*8);
    epv[0]=bf2f(q.x&0xffffu); epv[1]=bf2f(q.x>>16);
    epv[2]=bf2f(q.y&0xffffu); epv[3]=bf2f(q.y>>16);
    epv[4]=bf2f(q.z&0xffffu); epv[5]=bf2f(q.z>>16);
    epv[6]=bf2f(q.w&0xffffu); epv[7]=bf2f(q.w>>16);
  } else if constexpr(EPAD==2){
    u32 q=*(const u32*)(ep+(size_t)j*2);
    epv[0]=bf2f(q&0xffffu); epv[1]=bf2f(q>>16);
  } else {
    const uint4* qq=(const uint4*)(ep+(size_t)j*16);
    uint4 q0=qq[0], q1=qq[1];
    u32 w[8]={q0.x,q0.y,q0.z,q0.w,q1.x,q1.y,q1.z,q1.w};
    #pragma unroll
    for(int i=0;i<8;i++){
      if(2*i  <FO) epv[2*i  ]=bf2f(w[i]&0xffffu);
      if(2*i+1<FO) epv[2*i+1]=bf2f(w[i]>>16);
    }
  }
}

// ---------------- per-layer gather aggregation ----------------
// 4 lanes per node, 2 edges per lane per iteration: lane sub covers slots
// {j0+2*sub, j0+2*sub+1} + 8k. Typical degree <= 8 completes in ONE iteration
// with two independent gather chains in flight (2x MLP, half the dependent
// iteration count vs 1-edge/lane). No atomics anywhere.
template<int FO,int EPAD,int PO>
__global__ __launch_bounds__(256) void k_agg(
  const float* __restrict__ xl, const float* __restrict__ xr,
  const u32* __restrict__ off, const u16* __restrict__ srcs16,
  const u16* __restrict__ ep, const float* __restrict__ avec,
  const float* __restrict__ selfv, float* __restrict__ partial)
{
  const int t=threadIdx.x, p=blockIdx.y;
  const int n=blockIdx.x*64+(t>>2), sub=t&3;
  if(n>=NN) return;
  const int r=p*NN+n;
  float av[FO], xrn[FO];
  #pragma unroll
  for(int f=0;f<FO;f++) av[f]=avec[p*FO+f];
  load_row<FO,PO>(xr+(size_t)r*PO, xrn);

  float den=0.f, num[FO];
  #pragma unroll
  for(int f=0;f<FO;f++) num[f]=0.f;
  if(sub==0){
    float xln[FO];
    load_row<FO,PO>(xl+(size_t)r*PO, xln);
    float e=0.f;
    #pragma unroll
    for(int f=0;f<FO;f++){ float m=xln[f]+xrn[f]+selfv[p*16+f]; e+=lrelu(m)*av[f]; }
    float ex=__expf(e);
    den=ex;
    #pragma unroll
    for(int f=0;f<FO;f++) num[f]=ex*xln[f];
  }
  const u32 j0=off[r], j1=off[r+1];
  for(u32 j=j0+2*sub; j<j1; j+=8){
    const bool hasB=(j+1<j1);
    const u32 jB=hasB?(j+1):j;
    const u32 sA=srcs16[j];
    const u32 sB=srcs16[jB];
    float epA[FO], epB[FO];
    load_ep<FO,EPAD>(ep,j ,epA);
    load_ep<FO,EPAD>(ep,jB,epB);
    float xlsA[FO], xlsB[FO];
    load_row<FO,PO>(xl+((size_t)p*NN+sA)*PO, xlsA);
    load_row<FO,PO>(xl+((size_t)p*NN+sB)*PO, xlsB);
    float eA=0.f, eB=0.f;
    #pragma unroll
    for(int f=0;f<FO;f++){
      eA+=lrelu(xlsA[f]+xrn[f]+epA[f])*av[f];
      eB+=lrelu(xlsB[f]+xrn[f]+epB[f])*av[f];
    }
    const float exA=__expf(eA);
    const float exB=hasB?__expf(eB):0.f;
    den+=exA+exB;
    #pragma unroll
    for(int f=0;f<FO;f++) num[f]+=exA*xlsA[f]+exB*xlsB[f];
  }
  den+=__shfl_xor(den,1); den+=__shfl_xor(den,2);
  #pragma unroll
  for(int f=0;f<FO;f++){ num[f]+=__shfl_xor(num[f],1); num[f]+=__shfl_xor(num[f],2); }
  if(sub==0){
    const float inv=1.f/den;
    float* dst=partial+(size_t)r*PO;
    #pragma unroll
    for(int f=0;f<FO;f++) dst[f]=num[f]*inv;
  }
}

// ---------------- final combine (d3 output, 15 wide, no relu) ----------------
__global__ __launch_bounds__(256) void k_final15(
  const float* __restrict__ partial, const float* __restrict__ b,
  float* __restrict__ out)
{
  __shared__ float sbias[15];
  const int t=threadIdx.x;
  if(t<15){ float s=0.f; for(int p=0;p<PP;p++) s+=b[p*15+t]; sbias[t]=s; }
  __syncthreads();
  const int n=blockIdx.x*256+t;
  if(n>=NN) return;
  float s[15];
  #pragma unroll
  for(int f=0;f<15;f++) s[f]=sbias[f];
  #pragma unroll
  for(int p=0;p<PP;p++){
    const float* src=partial+((size_t)p*NN+n)*16;
    #pragma unroll
    for(int f=0;f<15;f++) s[f]+=src[f];
  }
  #pragma unroll
  for(int f=0;f<15;f++) out[(size_t)n*15+f]=s[f];
}

// ---------------- launch ----------------
extern "C" void kernel_launch(void* const* d_in, const int* in_sizes, int n_in,
                              void* d_out, int out_size, void* d_ws, size_t ws_size,
                              hipStream_t stream)
{
  const float* x =(const float*)d_in[0];
  const float* ea=(const float*)d_in[1];
  const int*   ei=(const int*)d_in[2];
  auto W=[&](int l,int k)->const float*{ return (const float*)d_in[3+5*l+k]; };

  char* base=(char*)d_ws; size_t cur=0;
  auto alloc=[&](size_t bytes)->char*{ char* pp=base+cur; cur=(cur+bytes+255)&~(size_t)255; return pp; };
  u32*  off    =(u32*) alloc((size_t)(PN+1)*4);
  u32*  hist   =(u32*) alloc((size_t)NBKT*NB2*4);  // per-(bucket,block) counts -> bases
  u32*  bcnt   =(u32*) alloc((size_t)NBKT*4);
  u32*  boff   =(u32*) alloc((size_t)(NBKT+1)*4);
  u16*  srcs16 =(u16*) alloc((size_t)EPT*2);
  u32*  eid    =(u32*) alloc((size_t)EPT*4);
  float* bpartP=(float*)alloc((size_t)PP*G2*64*4);
  float* selfvec=(float*)alloc(6*PP*16*4);
  float* xl    =(float*)alloc((size_t)PN*16*4);
  float* xr    =(float*)alloc((size_t)PN*16*4);
  float* partial=(float*)alloc((size_t)PN*16*4);
  u16*  ep0    =(u16*) alloc((size_t)EPT*8*2);
  u16*  ep1    =(u16*) alloc((size_t)EPT*8*2);
  u16*  ep2    =(u16*) alloc((size_t)EPT*2*2);
  u16*  ep3    =(u16*) alloc((size_t)EPT*8*2);
  u16*  ep4    =(u16*) alloc((size_t)EPT*8*2);
  u16*  ep5    =(u16*) alloc((size_t)EPT*16*2);
  // bedge aliases the first 16MB of ep5 (dead until k_eproj runs; stream-ordered)
  uint2* bedge =(uint2*)ep5;
  (void)ws_size; (void)in_sizes; (void)n_in; (void)out_size;

  dim3 b256(256);
  k_bhist    <<<dim3(NB2,PP),b256,0,stream>>>(ei,hist);
  k_bsum     <<<dim3(NBK,PP),dim3(128),0,stream>>>(hist,bcnt);
  k_bscan    <<<dim3(1),dim3(1024),0,stream>>>(bcnt,boff);
  k_bscatter2<<<dim3(NB2,PP),b256,0,stream>>>(ei,boff,hist,bedge);
  k_bfinal2  <<<dim3(NBK,PP),b256,0,stream>>>(bedge,boff,off,srcs16,eid);
  k_eproj_mfma<<<dim3(G2,PP),b256,0,stream>>>(ea,eid,
              W(0,2),W(1,2),W(2,2),W(3,2),W(4,2),W(5,2),
              ep0,ep1,ep2,ep3,ep4,ep5,bpartP);
  k_selfvec3<<<dim3(PP*64),dim3(64),0,stream>>>(bpartP,selfvec);

  dim3 gproj((NN+255)/256,PP), gagg((NN+63)/64,PP), gnode((NN+255)/256);

  // L0: e1 15->8
  k_proj<15,8><<<gproj,b256,0,stream>>>(x,15,W(0,0),W(0,1),xl,xr);
  k_agg<8,8,8>   <<<gagg ,b256,0,stream>>>(xl,xr,off,srcs16,ep0,W(0,3),selfvec+0*80,partial);
  k_comb<8,8,8,true><<<gnode,b256,0,stream>>>(partial,W(0,4),W(1,0),W(1,1),xl,xr);   // relu(e1) -> proj e2
  k_agg<8,8,8>   <<<gagg ,b256,0,stream>>>(xl,xr,off,srcs16,ep1,W(1,3),selfvec+1*80,partial);
  k_comb<8,2,2,true><<<gnode,b256,0,stream>>>(partial,W(1,4),W(2,0),W(2,1),xl,xr);   // relu(e2) -> proj e3
  k_agg<2,2,2>   <<<gagg ,b256,0,stream>>>(xl,xr,off,srcs16,ep2,W(2,3),selfvec+2*80,partial);
  k_comb<2,8,8,false><<<gnode,b256,0,stream>>>(partial,W(2,4),W(3,0),W(3,1),xl,xr);  // NO relu after e3 -> proj d1
  k_agg<8,8,8>   <<<gagg ,b256,0,stream>>>(xl,xr,off,srcs16,ep3,W(3,3),selfvec+3*80,partial);
  k_comb<8,8,8,true><<<gnode,b256,0,stream>>>(partial,W(3,4),W(4,0),W(4,1),xl,xr);   // relu(d1) -> proj d2
  k_agg<8,8,8>   <<<gagg ,b256,0,stream>>>(xl,xr,off,srcs16,ep4,W(4,3),selfvec+4*80,partial);
  k_comb<8,15,16,true><<<gnode,b256,0,stream>>>(partial,W(4,4),W(5,0),W(5,1),xl,xr); // relu(d2) -> proj d3 (pitch 16)
  k_agg<15,16,16><<<gagg ,b256,0,stream>>>(xl,xr,off,srcs16,ep5,W(5,3),selfvec+5*80,partial);
  k_final15<<<gnode,b256,0,stream>>>(partial,W(5,4),(float*)d_out);
}